// Round 1
// 345.691 us; speedup vs baseline: 1.0773x; 1.0773x over previous
//
#include <hip/hip_runtime.h>

// Fused Canny-style edge pipeline, 1x3x4096x4096 fp32 -> 1x4096x4096 fp32.
// R2: 32x32 tile, group-of-4-column vectorization, 22.8 KB LDS (6-7 blocks/CU).
// R3: Stage-D wave-level early-out on the [6,50] magnitude band (input stats
//     make keep ~never true), + guarded comparison-based orientation with
//     bit-exact atan2f fallback inside a 1e-4 guard band.

#define IMG_H 4096
#define IMG_W 4096

constexpr int TW = 32, TH = 32;
constexpr int HBH = 40, HBW = 40;  // hblur:   (r,c) -> abs (Y0-4+r, X0-2+c)
constexpr int BH  = 36, BW  = 40;  // blurred: (r,c) -> abs (Y0-2+r, X0-2+c)
constexpr int MH  = 34, MW  = 36;  // gradmag: (r,c) -> abs (Y0-1+r, X0-1+c)

__global__ __launch_bounds__(256, 6)
void canny_fused(const float* __restrict__ img,
                 const float* __restrict__ gauss,
                 float* __restrict__ out) {
  __shared__ float s_hb[HBH * HBW];  // per-channel horizontal blur (transient)
  __shared__ float s_bl[BH * BW];    // per-channel blurred (transient)
  __shared__ float s_bs[BH * BW];    // sum over channels of blurred
  __shared__ float s_mg[MH * MW];    // grad_mag summed over channels

  const int tid = threadIdx.x;
  const int X0 = blockIdx.x * TW;
  const int Y0 = blockIdx.y * TH;

  const float g0 = gauss[0], g1 = gauss[1], g2 = gauss[2],
              g3 = gauss[3], g4 = gauss[4];

  for (int ch = 0; ch < 3; ++ch) {
    const float* im = img + (size_t)ch * ((size_t)IMG_H * IMG_W);

    // ---- Stage A: horizontal gaussian, 4 cols per task (40 rows x 10 groups).
    // hblur col c <-> img col X0-2+c; group needs img cols X0-4+c0 .. X0+3+c0.
    for (int j = tid; j < HBH * 10; j += 256) {
      int r = j / 10, g = j - r * 10;
      int c0 = g * 4;
      int gy = Y0 - 4 + r;
      float4 o;
      if ((unsigned)gy < IMG_H) {
        int cb = X0 - 4 + c0;
        const float* row = im + (size_t)gy * IMG_W;
        float a0, a1, a2, a3, a4, a5, a6, a7;
        if (cb >= 0 && cb + 7 < IMG_W) {
          float4 va = *(const float4*)(row + cb);
          float4 vb = *(const float4*)(row + cb + 4);
          a0 = va.x; a1 = va.y; a2 = va.z; a3 = va.w;
          a4 = vb.x; a5 = vb.y; a6 = vb.z; a7 = vb.w;
        } else {
          float t[8];
#pragma unroll
          for (int u = 0; u < 8; ++u) {
            int x = cb + u;
            t[u] = ((unsigned)x < IMG_W) ? row[x] : 0.f;
          }
          a0 = t[0]; a1 = t[1]; a2 = t[2]; a3 = t[3];
          a4 = t[4]; a5 = t[5]; a6 = t[6]; a7 = t[7];
        }
        o.x = g0 * a0 + g1 * a1 + g2 * a2 + g3 * a3 + g4 * a4;
        o.y = g0 * a1 + g1 * a2 + g2 * a3 + g3 * a4 + g4 * a5;
        o.z = g0 * a2 + g1 * a3 + g2 * a4 + g3 * a5 + g4 * a6;
        o.w = g0 * a3 + g1 * a4 + g2 * a5 + g3 * a6 + g4 * a7;
      } else {
        o = make_float4(0.f, 0.f, 0.f, 0.f);
      }
      *(float4*)&s_hb[r * HBW + c0] = o;
    }
    __syncthreads();

    // ---- Stage B: vertical gaussian (36 rows x 10 groups). Force exact 0
    // outside the image (the Sobel conv zero-pads *blurred*).
    for (int j = tid; j < BH * 10; j += 256) {
      int r = j / 10, g = j - r * 10;
      int c0 = g * 4;
      float4 a0 = *(const float4*)&s_hb[(r    ) * HBW + c0];
      float4 a1 = *(const float4*)&s_hb[(r + 1) * HBW + c0];
      float4 a2 = *(const float4*)&s_hb[(r + 2) * HBW + c0];
      float4 a3 = *(const float4*)&s_hb[(r + 3) * HBW + c0];
      float4 a4 = *(const float4*)&s_hb[(r + 4) * HBW + c0];
      float4 v;
      v.x = g0 * a0.x + g1 * a1.x + g2 * a2.x + g3 * a3.x + g4 * a4.x;
      v.y = g0 * a0.y + g1 * a1.y + g2 * a2.y + g3 * a3.y + g4 * a4.y;
      v.z = g0 * a0.z + g1 * a1.z + g2 * a2.z + g3 * a3.z + g4 * a4.z;
      v.w = g0 * a0.w + g1 * a1.w + g2 * a2.w + g3 * a3.w + g4 * a4.w;
      int gy = Y0 - 2 + r;
      bool rok = (unsigned)gy < IMG_H;
      int gx0 = X0 - 2 + c0;
      v.x = (rok && (unsigned)(gx0    ) < IMG_W) ? v.x : 0.f;
      v.y = (rok && (unsigned)(gx0 + 1) < IMG_W) ? v.y : 0.f;
      v.z = (rok && (unsigned)(gx0 + 2) < IMG_W) ? v.z : 0.f;
      v.w = (rok && (unsigned)(gx0 + 3) < IMG_W) ? v.w : 0.f;
      *(float4*)&s_bl[r * BW + c0] = v;
      float4* ps = (float4*)&s_bs[r * BW + c0];
      if (ch == 0) {
        *ps = v;
      } else {
        float4 s = *ps;
        s.x += v.x; s.y += v.y; s.z += v.z; s.w += v.w;
        *ps = s;
      }
    }
    __syncthreads();

    // ---- Stage C: Sobel + magnitude, accumulate (34 rows x 9 groups).
    for (int j = tid; j < MH * 9; j += 256) {
      int r = j / 9, g = j - r * 9;
      int c0 = g * 4;
      float w0[6], w1[6], w2[6];
      {
        float4 p = *(const float4*)&s_bl[(r    ) * BW + c0];
        float2 q = *(const float2*)&s_bl[(r    ) * BW + c0 + 4];
        w0[0]=p.x; w0[1]=p.y; w0[2]=p.z; w0[3]=p.w; w0[4]=q.x; w0[5]=q.y;
      }
      {
        float4 p = *(const float4*)&s_bl[(r + 1) * BW + c0];
        float2 q = *(const float2*)&s_bl[(r + 1) * BW + c0 + 4];
        w1[0]=p.x; w1[1]=p.y; w1[2]=p.z; w1[3]=p.w; w1[4]=q.x; w1[5]=q.y;
      }
      {
        float4 p = *(const float4*)&s_bl[(r + 2) * BW + c0];
        float2 q = *(const float2*)&s_bl[(r + 2) * BW + c0 + 4];
        w2[0]=p.x; w2[1]=p.y; w2[2]=p.z; w2[3]=p.w; w2[4]=q.x; w2[5]=q.y;
      }
      int gy = Y0 - 1 + r;
      bool rok = (unsigned)gy < IMG_H;
      float res[4];
#pragma unroll
      for (int e = 0; e < 4; ++e) {
        float gxv = w0[e] - w0[e + 2] + 2.f * w1[e] - 2.f * w1[e + 2] + w2[e] - w2[e + 2];
        float gyv = w0[e] + 2.f * w0[e + 1] + w0[e + 2] - w2[e] - 2.f * w2[e + 1] - w2[e + 2];
        float m = sqrtf(gxv * gxv + gyv * gyv + 1e-8f);
        int gx = X0 - 1 + c0 + e;
        res[e] = (rok && (unsigned)gx < IMG_W) ? m : 0.f;
      }
      float4* pd = (float4*)&s_mg[r * MW + c0];
      if (ch == 0) {
        *pd = make_float4(res[0], res[1], res[2], res[3]);
      } else {
        float4 s = *pd;
        s.x += res[0]; s.y += res[1]; s.z += res[2]; s.w += res[3];
        *pd = s;
      }
    }
    __syncthreads();
  }

  // ---- Stage D: orientation + NMS + threshold; 4 outputs per thread.
  // keep requires mc in [6,50]; with this input's statistics that is ~never
  // true, so ballot-skip the whole orientation/NMS block per wave.
  {
    const int ty  = tid >> 3;         // 0..31
    const int tx0 = (tid & 7) << 2;   // 0..28 step 4
    const int row1 = (ty + 1) * MW;

    // centers mc_e = s_mg[row1 + tx0+1+e], e=0..3 — read as two aligned b128
    // (conflict-free) instead of 4 scalar reads (8-way bank conflict).
    float4 q0 = *(const float4*)&s_mg[row1 + tx0];
    float4 q1 = *(const float4*)&s_mg[row1 + tx0 + 4];
    float mcs[4];
    mcs[0] = q0.y; mcs[1] = q0.z; mcs[2] = q0.w; mcs[3] = q1.x;

    bool band = false;
#pragma unroll
    for (int e = 0; e < 4; ++e)
      band = band || (mcs[e] >= 6.0f && mcs[e] <= 50.0f);

    float4 resv = make_float4(0.f, 0.f, 0.f, 0.f);
    if (__ballot(band) != 0ULL) {
      // Rare path: full Sobel-on-summed-blur + orientation + NMS, identical
      // decision logic to R2.
      float w0[8], w1[8], w2[8];
#pragma unroll
      for (int rr = 0; rr < 3; ++rr) {
        float* w = (rr == 0) ? w0 : (rr == 1) ? w1 : w2;
        float4 p = *(const float4*)&s_bs[(ty + 1 + rr) * BW + tx0];
        float4 q = *(const float4*)&s_bs[(ty + 1 + rr) * BW + tx0 + 4];
        w[0]=p.x; w[1]=p.y; w[2]=p.z; w[3]=p.w; w[4]=q.x; w[5]=q.y; w[6]=q.z; w[7]=q.w;
      }
      const unsigned long long off_tbl = 0xDDDCDBFF23242501ULL;
      float res[4];
#pragma unroll
      for (int e = 0; e < 4; ++e) {
        int tx = tx0 + e;
        float b00 = w0[e + 1], b01 = w0[e + 2], b02 = w0[e + 3];
        float b10 = w1[e + 1],                  b12 = w1[e + 3];
        float b20 = w2[e + 1], b21 = w2[e + 2], b22 = w2[e + 3];
        float gxs = b00 - b02 + 2.f * b10 - 2.f * b12 + b20 - b22;
        float gys = b00 + 2.f * b01 + b02 - b20 - 2.f * b21 - b22;
        // NMS is symmetric in +/-off, so only the sector mod 180deg matters:
        // compare |gys| against tan(22.5~)*|gxs| and tan(67.5~)*|gxs|.
        // Within a 1e-4 relative guard band of the thresholds (>=100x the
        // fp32 pipeline's boundary uncertainty), fall back to the exact
        // atan2f path so classification is bit-identical to R2.
        float ax = fabsf(gxs), ay = fabsf(gys);
        float f1 = ay - 0.41421356f * ax;
        float f2 = ay - 2.4142137f * ax;
        int off;
        if (fminf(fabsf(f1), fabsf(f2)) < 1e-4f * (ax + ay)) {
          float ori = atan2f(gys, gxs) * 57.295827908797776f + 180.0f;  // 180/3.14159
          int k = (int)rintf(ori / 45.0f);   // round-half-even like jnp.round
          int ip = k & 7;
          off = (int)(signed char)(off_tbl >> (ip * 8));
        } else {
          off = (f1 <= 0.f) ? 1
              : (f2 >= 0.f) ? MW
              : (((__float_as_uint(gxs) ^ __float_as_uint(gys)) >> 31) ? (MW - 1)
                                                                       : (MW + 1));
        }
        int ctr = row1 + (tx + 1);
        float mc  = mcs[e];
        float csp = mc - s_mg[ctr + off];
        float csn = mc - s_mg[ctr - off];
        bool is_max = fminf(csp, csn) > 0.0f;
        bool keep = is_max && (mc >= 6.0f) && (mc <= 50.0f);
        res[e] = keep ? 1.0f : 0.0f;
      }
      resv = make_float4(res[0], res[1], res[2], res[3]);
    }
    *(float4*)&out[(size_t)(Y0 + ty) * IMG_W + (X0 + tx0)] = resv;
  }
}

extern "C" void kernel_launch(void* const* d_in, const int* in_sizes, int n_in,
                              void* d_out, int out_size, void* d_ws, size_t ws_size,
                              hipStream_t stream) {
  const float* img   = (const float*)d_in[0];
  const float* gauss = (const float*)d_in[1];
  float* out = (float*)d_out;
  dim3 grid(IMG_W / TW, IMG_H / TH);
  canny_fused<<<grid, 256, 0, stream>>>(img, gauss, out);
}